// Round 1
// 324.548 us; speedup vs baseline: 1.0141x; 1.0141x over previous
//
#include <hip/hip_runtime.h>
#include <math.h>

#define L3 2197            // 13^3
#define SP 2200            // bf16 elems per padded volume (4400 B, 16B-aligned)
#define NV (SP / 8)        // 275 uint4 chunks of 8 bf16
#define NT 256             // 4 waves/block: 8 blocks/CU (LDS 8x19968B=156KB), 32 waves/CU

// Single in-place LDS buffer: peak stage size 17^3
#define SSZ 4913

typedef unsigned int u32;

// round-to-nearest-even bf16 pack of two floats -> one u32 (lo = a, hi = b)
__device__ __forceinline__ u32 pack2bf(float a, float b) {
    u32 ua = __float_as_uint(a);
    u32 ub = __float_as_uint(b);
    ua = (ua + 0x7fffu + ((ua >> 16) & 1u)) >> 16;
    ub = (ub + 0x7fffu + ((ub >> 16) & 1u)) & 0xffff0000u;
    return ua | ub;
}

__device__ __forceinline__ void unpack8(uint4 v, float* f) {
    f[0] = __uint_as_float(v.x << 16);
    f[1] = __uint_as_float(v.x & 0xffff0000u);
    f[2] = __uint_as_float(v.y << 16);
    f[3] = __uint_as_float(v.y & 0xffff0000u);
    f[4] = __uint_as_float(v.z << 16);
    f[5] = __uint_as_float(v.z & 0xffff0000u);
    f[6] = __uint_as_float(v.w << 16);
    f[7] = __uint_as_float(v.w & 0xffff0000u);
}

__device__ __forceinline__ uint4 pack8(const float* f) {
    uint4 v;
    v.x = pack2bf(f[0], f[1]);
    v.y = pack2bf(f[2], f[3]);
    v.z = pack2bf(f[4], f[5]);
    v.w = pack2bf(f[6], f[7]);
    return v;
}

// Sliding clamped max-of-3 (edge-pad 3 + maxpool3 VALID): x[13] -> o[17]
__device__ __forceinline__ void maxpool_row(const float* x, float* o) {
    float p[12];
#pragma unroll
    for (int i = 0; i < 12; ++i) p[i] = fmaxf(x[i], x[i + 1]);
    o[0] = x[0];
    o[1] = x[0];
    o[2] = p[0];
#pragma unroll
    for (int j = 3; j <= 13; ++j) o[j] = fmaxf(p[j - 3], x[j - 1]);
    o[14] = p[11];
    o[15] = x[12];
    o[16] = x[12];
}

// Two stacked avgpool3 == 5-tap triangle [1,2,3,2,1] (scale applied): y[17] -> o[13]
__device__ __forceinline__ void tri_row(const float* y, float* o, float scale) {
#pragma unroll
    for (int c = 0; c < 13; ++c) {
        float s = fmaf(2.0f, y[c + 1], y[c]);
        s = fmaf(3.0f, y[c + 2], s);
        s = fmaf(2.0f, y[c + 3], s);
        o[c] = (s + y[c + 4]) * scale;
    }
}

// S holds (13,13,13) input (c fastest); on return S[0..2196] = smooth(S).
// In-place single-buffer, 5 stages: M_c, M_b, (M_a + C_a fused), C_b, C_c.
// Valid: all maxes precede all convs; convs commute among themselves.
// Stage shapes: 2197 -> 2873 -> 4913 -> (4913, a:17->13 in place) -> 2873 -> 2197
__device__ void smooth_single(float* S, int tid) {
    __syncthreads();   // make caller's fill visible
    // M_c along c: (13,13,13) -> (13,13,17); 169 row pencils
    {
        const bool act = tid < 169;
        float x[13], o[17];
        if (act) {
            const float* src = S + tid * 13;
#pragma unroll
            for (int i = 0; i < 13; ++i) x[i] = src[i];
            maxpool_row(x, o);
        }
        __syncthreads();
        if (act) {
            float* d = S + tid * 17;
#pragma unroll
            for (int i = 0; i < 17; ++i) d[i] = o[i];
        }
        __syncthreads();
    }
    // M_b along b: (13,13,17) -> (13,17,17); 221 pencils (a,c)
    {
        const bool act = tid < 221;
        const int a = tid / 17, c = tid % 17;
        float x[13], o[17];
        if (act) {
            const float* src = S + a * 221 + c;
#pragma unroll
            for (int i = 0; i < 13; ++i) x[i] = src[i * 17];
            maxpool_row(x, o);
        }
        __syncthreads();
        if (act) {
            float* d = S + a * 289 + c;
#pragma unroll
            for (int i = 0; i < 17; ++i) d[i * 17] = o[i];
        }
        __syncthreads();
    }
    // M_a + C_a fused: a-axis max (13->17) then a-axis conv (17->13), all in
    // registers, in-place per (b,c) column (stride 289, own column, no barrier).
    // 289 columns on 256 threads: strided second pass, column exclusively owned.
    for (int p = tid; p < 289; p += NT) {
        float x[13], m[17], o[13];
        const float* src = S + p;
#pragma unroll
        for (int i = 0; i < 13; ++i) x[i] = src[i * 289];
        maxpool_row(x, m);
        tri_row(m, o, 1.0f);
        float* d = S + p;
#pragma unroll
        for (int i = 0; i < 13; ++i) d[i * 289] = o[i];
    }
    __syncthreads();
    // C_b along b: (13,17,17) -> (13,13,17); 221 pencils (a,c), a in 0..12
    {
        const bool act = tid < 221;
        const int a = tid / 17, c = tid % 17;
        float y[17], o[13];
        if (act) {
            const float* src = S + a * 289 + c;
#pragma unroll
            for (int i = 0; i < 17; ++i) y[i] = src[i * 17];
            tri_row(y, o, 1.0f);
        }
        __syncthreads();
        if (act) {
            float* d = S + a * 221 + c;
#pragma unroll
            for (int i = 0; i < 13; ++i) d[i * 17] = o[i];
        }
        __syncthreads();
    }
    // C_c along c: (13,13,17) -> (13,13,13); 169 row pencils, scale 1/729
    {
        const bool act = tid < 169;
        float y[17], o[13];
        if (act) {
            const float* src = S + tid * 17;
#pragma unroll
            for (int i = 0; i < 17; ++i) y[i] = src[i];
            tri_row(y, o, 1.0f / 729.0f);
        }
        __syncthreads();
        if (act) {
            float* d = S + tid * 13;
#pragma unroll
            for (int i = 0; i < 13; ++i) d[i] = o[i];
        }
        __syncthreads();
    }
}

// tmp1 = smooth(a1 + a0*cost) as bf16; preA = a4 + a2*(a1 + a0*cost) as bf16
__global__ __launch_bounds__(NT) void k_smooth1(
        const float* __restrict__ cost, const float* __restrict__ alpha,
        uint4* __restrict__ tmp1, uint4* __restrict__ preA) {
    __shared__ alignas(16) float S[SSZ];
    const int n = blockIdx.x;
    const int tid = threadIdx.x;
    const float a0 = alpha[0], a1 = alpha[1], a2 = alpha[2], a4 = alpha[4];
    const float* src = cost + (size_t)n * L3;
    for (int i = tid; i < L3; i += NT) S[i] = fmaf(a0, src[i], a1);
    if (tid < SP - L3) S[L3 + tid] = 0.0f;   // pad for pack loop
    __syncthreads();
    uint4* pre = preA + (size_t)n * NV;
    for (int i = tid; i < NV; i += NT) {
        float f[8];
#pragma unroll
        for (int j = 0; j < 8; ++j) f[j] = fmaf(a2, S[8 * i + j], a4);
        pre[i] = pack8(f);
    }
    smooth_single(S, tid);
    uint4* dst = tmp1 + (size_t)n * NV;
    for (int i = tid; i < NV; i += NT) {
        float f[8];
        const int base = 8 * i;
#pragma unroll
        for (int j = 0; j < 8; ++j) f[j] = (base + j < L3) ? S[base + j] : 0.0f;
        dst[i] = pack8(f);
    }
}

// tmp2 = smooth(preA + (a3/norm) * sum_k w_k * tmp1[knn_k]) as bf16
__global__ __launch_bounds__(NT) void k_mid(
        const int* __restrict__ knn, const float* __restrict__ dist,
        const float* __restrict__ alpha, const uint4* __restrict__ tmp1,
        const uint4* __restrict__ preA, uint4* __restrict__ tmp2, int K) {
    __shared__ alignas(16) float S[SSZ];
    __shared__ float s_w[8];
    const int n = blockIdx.x;
    const int tid = threadIdx.x;
    if (tid < K) s_w[tid] = expf(-dist[n * K + tid] * (1.0f / 200.0f));
    __syncthreads();
    float norm = 0.0f;
    for (int k = 0; k < K; ++k) norm += s_w[k];
    const float sc = alpha[3] / norm;

    const uint4* ptr[8];
    float wk[8];
    for (int k = 0; k < K; ++k) {
        ptr[k] = tmp1 + (size_t)knn[n * K + k] * NV;
        wk[k] = s_w[k];
    }
    const uint4* pre = preA + (size_t)n * NV;
    for (int i = tid; i < NV; i += NT) {
        float f[8], acc[8], g[8];
        unpack8(pre[i], f);
#pragma unroll
        for (int j = 0; j < 8; ++j) acc[j] = 0.0f;
#pragma unroll 8
        for (int k = 0; k < K; ++k) {
            unpack8(ptr[k][i], g);
#pragma unroll
            for (int j = 0; j < 8; ++j) acc[j] = fmaf(wk[k], g[j], acc[j]);
        }
#pragma unroll
        for (int j = 0; j < 8; ++j) S[8 * i + j] = fmaf(sc, acc[j], f[j]);
    }
    smooth_single(S, tid);
    uint4* dst = tmp2 + (size_t)n * NV;
    for (int i = tid; i < NV; i += NT) {
        float f[8];
        const int base = 8 * i;
#pragma unroll
        for (int j = 0; j < 8; ++j) f[j] = (base + j < L3) ? S[base + j] : 0.0f;
        dst[i] = pack8(f);
    }
}

// out = (a5/norm) * sum_k w_k * tmp2[knn_k]   (fp32 output)
__global__ __launch_bounds__(NT) void k_out(
        const int* __restrict__ knn, const float* __restrict__ dist,
        const float* __restrict__ alpha, const uint4* __restrict__ tmp2,
        float* __restrict__ out, int K) {
    __shared__ float s_w[8];
    const int n = blockIdx.x;
    const int tid = threadIdx.x;
    if (tid < K) s_w[tid] = expf(-dist[n * K + tid] * (1.0f / 200.0f));
    __syncthreads();
    float norm = 0.0f;
    for (int k = 0; k < K; ++k) norm += s_w[k];
    const float sc = alpha[5] / norm;

    const uint4* ptr[8];
    float wk[8];
    for (int k = 0; k < K; ++k) {
        ptr[k] = tmp2 + (size_t)knn[n * K + k] * NV;
        wk[k] = s_w[k];
    }
    float* dst = out + (size_t)n * L3;
    for (int i = tid; i < NV; i += NT) {
        float acc[8], g[8];
#pragma unroll
        for (int j = 0; j < 8; ++j) acc[j] = 0.0f;
#pragma unroll 8
        for (int k = 0; k < K; ++k) {
            unpack8(ptr[k][i], g);
#pragma unroll
            for (int j = 0; j < 8; ++j) acc[j] = fmaf(wk[k], g[j], acc[j]);
        }
        const int base = 8 * i;
#pragma unroll
        for (int j = 0; j < 8; ++j)
            if (base + j < L3) dst[base + j] = sc * acc[j];
    }
}

extern "C" void kernel_launch(void* const* d_in, const int* in_sizes, int n_in,
                              void* d_out, int out_size, void* d_ws, size_t ws_size,
                              hipStream_t stream) {
    const float* cost  = (const float*)d_in[0];
    const int*   knn   = (const int*)d_in[1];
    const float* dist  = (const float*)d_in[2];
    const float* alpha = (const float*)d_in[3];
    float* out = (float*)d_out;

    const int N = in_sizes[0] / L3;
    int K = in_sizes[1] / N;
    if (K > 8) K = 8;

    // workspace: three bf16 volume arrays, each N*NV uint4 (N*4400 bytes)
    uint4* tmp1 = (uint4*)d_ws;
    uint4* tmp2 = tmp1 + (size_t)N * NV;
    uint4* preA = tmp2 + (size_t)N * NV;

    k_smooth1<<<N, NT, 0, stream>>>(cost, alpha, tmp1, preA);
    k_mid<<<N, NT, 0, stream>>>(knn, dist, alpha, tmp1, preA, tmp2, K);
    k_out<<<N, NT, 0, stream>>>(knn, dist, alpha, tmp2, out, K);
}